// Round 12
// baseline (133.353 us; speedup 1.0000x reference)
//
#include <hip/hip_runtime.h>

#define B 2
#define N 64
#define D 256
#define H 8
#define DK 32
#define M (B * N * N) // 8192

typedef __attribute__((ext_vector_type(8))) short bf16x8;
typedef __attribute__((ext_vector_type(4))) float f32x4;

// P is head-major: 4 proj planes of [b][h][r1*64+r2][32] bf16
#define PROJ_ELEMS (2097152)  // B*H*4096*32

__device__ __forceinline__ ushort f2b(float f) {
    union { float f; unsigned u; } v; v.f = f;
    unsigned r = v.u + 0x7fffu + ((v.u >> 16) & 1u); // RNE
    return (ushort)(r >> 16);
}
__device__ __forceinline__ float b2f(ushort u) {
    union { unsigned u; float f; } v; v.u = ((unsigned)u) << 16; return v.f;
}
// convert 8 bf16 (packed in a float4 register) to 8 floats
__device__ __forceinline__ void cvt8(float4 raw, float* f) {
    const ushort* s = (const ushort*)&raw;
#pragma unroll
    for (int j = 0; j < 8; ++j) f[j] = b2f(s[j]);
}

// async 16B/lane global->LDS (dst = wave-uniform base + lane*16)
__device__ __forceinline__ void glds16(const ushort* g, ushort* l) {
    __builtin_amdgcn_global_load_lds(
        (const __attribute__((address_space(1))) unsigned int*)g,
        (__attribute__((address_space(3))) unsigned int*)l, 16, 0, 0);
}

// ---------------------------------------------------------------------------
// Cast: state f32 -> bf16; 5 weights -> Wcat[1280][256] bf16; biases -> f32.
// ---------------------------------------------------------------------------
__global__ __launch_bounds__(256) void cast_all(const float* __restrict__ state,
                                                const float* __restrict__ W_lk, const float* __restrict__ W_rk,
                                                const float* __restrict__ W_lv, const float* __restrict__ W_rv,
                                                const float* __restrict__ W_o,
                                                const float* __restrict__ b_lk, const float* __restrict__ b_rk,
                                                const float* __restrict__ b_lv, const float* __restrict__ b_rv,
                                                const float* __restrict__ b_o,
                                                ushort* __restrict__ state_bf,
                                                ushort* __restrict__ Wcat,
                                                float* __restrict__ bias_cat) {
    const int gid = blockIdx.x * 256 + threadIdx.x;
    const float* Ws[5] = {W_lk, W_rk, W_lv, W_rv, W_o};
    const float* bs[5] = {b_lk, b_rk, b_lv, b_rv, b_o};

    if (gid < 1280) bias_cat[gid] = bs[gid >> 8][gid & 255];

    if (gid < 524288) {
        float4 v = *(const float4*)&state[(size_t)gid * 4];
        ushort4 o = {f2b(v.x), f2b(v.y), f2b(v.z), f2b(v.w)};
        *(ushort4*)&state_bf[(size_t)gid * 4] = o;
    } else {
        int u = gid - 524288;            // 0..81919
        int row = u >> 6;                // 0..1279
        int k4 = (u & 63) * 4;
        const float* W = Ws[row >> 8];
        float4 v = *(const float4*)&W[(size_t)(row & 255) * 256 + k4];
        ushort4 o = {f2b(v.x), f2b(v.y), f2b(v.z), f2b(v.w)};
        *(ushort4*)&Wcat[(size_t)row * 256 + k4] = o;
    }
}

// ---------------------------------------------------------------------------
// bf16 MFMA GEMM, m97-style. 128x128 tile, 4 waves, 4x4 16x16x32 frags, BK=32.
// RELAYOUT=1 (proj): scatter C into head-major P planes.
// ---------------------------------------------------------------------------
template <int BF16OUT, int RELAYOUT>
__global__ __launch_bounds__(256) void gemm_mfma(const ushort* __restrict__ A,
                                                 const ushort* __restrict__ Bw,
                                                 const float* __restrict__ bias,
                                                 void* __restrict__ Cv, int ldc) {
    __shared__ __align__(16) ushort As[128 * 32];
    __shared__ __align__(16) ushort Bs[128 * 32];
    const int tid = threadIdx.x;
    const int lane = tid & 63;
    const int wave = tid >> 6;
    const int wm = (wave & 1) * 64;
    const int wn = (wave >> 1) * 64;
    const int row0 = blockIdx.x * 128;
    const int col0 = blockIdx.y * 128;

    const int lr = lane >> 2;        // 0..15
    const int lkq = (lane & 3) * 8;  // {0,8,16,24}

    const ushort* gA0 = A + (size_t)(row0 + wave * 32 + lr) * 256 + lkq;
    const ushort* gA1 = gA0 + 16 * 256;
    const ushort* gB0 = Bw + (size_t)(col0 + wave * 32 + lr) * 256 + lkq;
    const ushort* gB1 = gB0 + 16 * 256;
    ushort* lA0 = &As[(wave * 32) * 32];
    ushort* lA1 = &As[(wave * 32 + 16) * 32];
    ushort* lB0 = &Bs[(wave * 32) * 32];
    ushort* lB1 = &Bs[(wave * 32 + 16) * 32];

    const int fr = lane & 15;
    const int fk = (lane >> 4) * 8;

    f32x4 acc[4][4] = {};

    for (int k0 = 0; k0 < 256; k0 += 32) {
        __syncthreads();
        glds16(gA0 + k0, lA0);
        glds16(gA1 + k0, lA1);
        glds16(gB0 + k0, lB0);
        glds16(gB1 + k0, lB1);
        __syncthreads();

        bf16x8 af[4], bf[4];
#pragma unroll
        for (int i = 0; i < 4; ++i)
            af[i] = *(const bf16x8*)&As[(wm + i * 16 + fr) * 32 + fk];
#pragma unroll
        for (int j = 0; j < 4; ++j)
            bf[j] = *(const bf16x8*)&Bs[(wn + j * 16 + fr) * 32 + fk];
#pragma unroll
        for (int i = 0; i < 4; ++i)
#pragma unroll
            for (int j = 0; j < 4; ++j)
                acc[i][j] = __builtin_amdgcn_mfma_f32_16x16x32_bf16(af[i], bf[j], acc[i][j], 0, 0, 0);
    }

#pragma unroll
    for (int j = 0; j < 4; ++j) {
        const int col = col0 + wn + j * 16 + (lane & 15);
        const float bv = bias[col];
#pragma unroll
        for (int i = 0; i < 4; ++i) {
            const int rbase = row0 + wm + i * 16 + (lane >> 4) * 4;
#pragma unroll
            for (int r = 0; r < 4; ++r) {
                float o = acc[i][j][r] + bv;
                if (RELAYOUT) {
                    const int row = rbase + r;
                    const int bb = row >> 12, rr = row & 4095;
                    const int proj = col >> 8, hh = (col >> 5) & 7, dk = col & 31;
                    ((ushort*)Cv)[(size_t)proj * PROJ_ELEMS +
                                  ((size_t)(bb * 8 + hh) * 4096 + rr) * 32 + dk] = f2b(o);
                } else if (BF16OUT) {
                    ((ushort*)Cv)[(size_t)(rbase + r) * ldc + col] = f2b(o);
                } else {
                    ((float*)Cv)[(size_t)(rbase + r) * ldc + col] = o;
                }
            }
        }
    }
}

// ---------------------------------------------------------------------------
// FUSED scores + online-softmax + gated combine, v7 = v5 (R10, best) +
// software pipeline. Tile = 16x x 16y per (b,h); grid (4,4,16) = 256 blocks,
// 512 threads (8 waves), a-chunk = 16, 3 barriers/chunk, LDS ~112 KB.
// Pipeline: chunk c+1's global loads (LV/RV raw, LK/RK MFMA frags, mask) AND
// its masked/scaled score MFMA are executed into REGISTERS before chunk c's
// gate phase (MFMA+VALU co-schedule); phase 1 of c+1 only commits registers
// to LDS. Hides global + MFMA latency behind gate/softmax.
// No launch_bounds min-waves (R9 lesson: forcing it spills).
// ---------------------------------------------------------------------------
__global__ __launch_bounds__(512) void fused_attn(const ushort* __restrict__ P,
                                                  const unsigned char* __restrict__ mask,
                                                  ushort* __restrict__ xbuf) {
    __shared__ __align__(16) float LVs[16 * 16 * 44];
    __shared__ __align__(16) float RVs[16 * 16 * 44];
    __shared__ __align__(16) float atts[16 * 16 * 20];
    __shared__ float mstate[16 * 20];
    __shared__ float lstate[16 * 20];
    __shared__ float alphas[16 * 20];

    const int bh = blockIdx.z;
    const int b = bh >> 3, h = bh & 7;
    const int x0 = blockIdx.x * 16, y0 = blockIdx.y * 16;
    const int tid = threadIdx.x;
    const int lane = tid & 63, wave = tid >> 6;

    const size_t HB = (size_t)bh * 4096 * 32;   // head slice offset (elements)
    const ushort* PLK = P + HB;
    const ushort* PRK = P + (size_t)1 * PROJ_ELEMS + HB;
    const ushort* PLV = P + (size_t)2 * PROJ_ELEMS + HB;
    const ushort* PRV = P + (size_t)3 * PROJ_ELEMS + HB;

    // gate coords: x = wave*2 + i, y = y2*4 + j, d = 2*dp + {0,1}
    const int y2 = (tid >> 4) & 3, dp = tid & 15;
    // softmax coords (threads 0..255)
    const int sx = tid >> 4, sy = tid & 15;
    if (tid < 256) {
        mstate[sx * 20 + sy] = -3.0e38f;
        lstate[sx * 20 + sy] = 0.0f;
    }

    float2 acc[2][4] = {};
    const float scale = 0.17677669529663687f; // 1/sqrt(32)

    // ---- pipeline registers ----
    float4 plv[2], prv[2];   // raw bf16x8 payloads for LV/RV staging
    f32x4 sreg[2];           // masked+scaled scores for a = wave*2 + {0,1}

    const int fr = lane & 15, fk = (lane >> 4) * 8;
    const int yq = lane & 15, xq = (lane >> 4) * 4;

    // prefetch chunk at 'ac': globals + score MFMA into registers
    auto prefetch = [&](int ac) {
#pragma unroll
        for (int it = 0; it < 2; ++it) {
            const int row = (tid >> 2) + it * 128;  // a*16 + r
            const int q = tid & 3;
            const int a = row >> 4, r = row & 15;
            plv[it] = *(const float4*)&PLV[((size_t)(x0 + r) * 64 + ac + a) * 32 + q * 8];
            prv[it] = *(const float4*)&PRV[((size_t)(ac + a) * 64 + y0 + r) * 32 + q * 8];
        }
#pragma unroll
        for (int aw = 0; aw < 2; ++aw) {
            const int a = wave * 2 + aw;
            bf16x8 af = *(const bf16x8*)&PLK[((size_t)(x0 + fr) * 64 + ac + a) * 32 + fk];
            bf16x8 bf = *(const bf16x8*)&PRK[((size_t)(ac + a) * 64 + y0 + fr) * 32 + fk];
            f32x4 s = {};
            s = __builtin_amdgcn_mfma_f32_16x16x32_bf16(af, bf, s, 0, 0, 0);
#pragma unroll
            for (int rr = 0; rr < 4; ++rr) {
                float sv = s[rr] * scale;
                if (mask[((size_t)(b * N + x0 + xq + rr) * N + ac + a) * N + y0 + yq]) sv = -1000.0f;
                s[rr] = sv;
            }
            sreg[aw] = s;
        }
    };

    prefetch(0);

    for (int ac = 0; ac < N; ac += 16) {
        __syncthreads();
        // ---- phase 1: commit prefetched registers to LDS ----
        {
#pragma unroll
            for (int it = 0; it < 2; ++it) {
                const int row = (tid >> 2) + it * 128;
                const int q = tid & 3;
                float f[8];
                cvt8(plv[it], f);
                *(float4*)&LVs[row * 44 + q * 8]     = make_float4(f[0], f[1], f[2], f[3]);
                *(float4*)&LVs[row * 44 + q * 8 + 4] = make_float4(f[4], f[5], f[6], f[7]);
                cvt8(prv[it], f);
                *(float4*)&RVs[row * 44 + q * 8]     = make_float4(f[0], f[1], f[2], f[3]);
                *(float4*)&RVs[row * 44 + q * 8 + 4] = make_float4(f[4], f[5], f[6], f[7]);
            }
#pragma unroll
            for (int aw = 0; aw < 2; ++aw) {
                const int a = wave * 2 + aw;
#pragma unroll
                for (int rr = 0; rr < 4; ++rr)
                    atts[(a * 16 + xq + rr) * 20 + yq] = sreg[aw][rr];
            }
        }
        __syncthreads();

        // ---- phase 2: online softmax over 16-a chunk (threads 0..255) ----
        if (tid < 256) {
            float s16[16];
            float mc = -3.0e38f;
#pragma unroll
            for (int a = 0; a < 16; ++a) {
                s16[a] = atts[(a * 16 + sx) * 20 + sy];
                mc = fmaxf(mc, s16[a]);
            }
            const float mold = mstate[sx * 20 + sy];
            const float mnew = fmaxf(mold, mc);
            const float alpha = __expf(mold - mnew);
            float ps = 0.0f;
#pragma unroll
            for (int a = 0; a < 16; ++a) {
                float p = __expf(s16[a] - mnew);
                atts[(a * 16 + sx) * 20 + sy] = p;
                ps += p;
            }
            lstate[sx * 20 + sy] = lstate[sx * 20 + sy] * alpha + ps;
            mstate[sx * 20 + sy] = mnew;
            alphas[sx * 20 + sy] = alpha;
        }
        __syncthreads();

        // ---- phase 3a: prefetch next chunk (hidden behind gate) ----
        if (ac + 16 < N) prefetch(ac + 16);

        // ---- phase 3b: rescale + gate ----
#pragma unroll
        for (int i = 0; i < 2; ++i) {
            const int x = wave * 2 + i;
            float4 av = *(const float4*)&alphas[x * 20 + y2 * 4];
            const float* ap = (const float*)&av;
#pragma unroll
            for (int j = 0; j < 4; ++j) {
                acc[i][j].x *= ap[j];
                acc[i][j].y *= ap[j];
            }
        }
#pragma unroll
        for (int a = 0; a < 16; ++a) {
            float2 lv[2], rv[4];
#pragma unroll
            for (int i = 0; i < 2; ++i)
                lv[i] = *(const float2*)&LVs[(a * 16 + wave * 2 + i) * 44 + dp * 2];
#pragma unroll
            for (int j = 0; j < 4; ++j)
                rv[j] = *(const float2*)&RVs[(a * 16 + y2 * 4 + j) * 44 + dp * 2];
#pragma unroll
            for (int i = 0; i < 2; ++i) {
                float4 wv = *(const float4*)&atts[(a * 16 + wave * 2 + i) * 20 + y2 * 4];
                const float* wp = (const float*)&wv;
#pragma unroll
                for (int j = 0; j < 4; ++j) {
                    acc[i][j].x += (wp[j] * lv[i].x) * rv[j].x;
                    acc[i][j].y += (wp[j] * lv[i].y) * rv[j].y;
                }
            }
        }
    }

    // ---- epilogue: divide by l, store bf16 ----
#pragma unroll
    for (int i = 0; i < 2; ++i) {
        const int x = wave * 2 + i;
        float4 lq = *(const float4*)&lstate[x * 20 + y2 * 4];
        const float* lp = (const float*)&lq;
#pragma unroll
        for (int j = 0; j < 4; ++j) {
            const float il = 1.0f / lp[j];
            ushort2 o = {f2b(acc[i][j].x * il), f2b(acc[i][j].y * il)};
            *(ushort2*)&xbuf[(((size_t)b * N + x0 + x) * N + y0 + y2 * 4 + j) * D + h * DK + 2 * dp] = o;
        }
    }
}

// ---------------------------------------------------------------------------
extern "C" void kernel_launch(void* const* d_in, const int* in_sizes, int n_in,
                              void* d_out, int out_size, void* d_ws, size_t ws_size,
                              hipStream_t stream) {
    const float* state = (const float*)d_in[0];
    const unsigned char* mask = (const unsigned char*)d_in[1];
    const float* W_lk = (const float*)d_in[2];
    const float* b_lk = (const float*)d_in[3];
    const float* W_rk = (const float*)d_in[4];
    const float* b_rk = (const float*)d_in[5];
    const float* W_lv = (const float*)d_in[6];
    const float* b_lv = (const float*)d_in[7];
    const float* W_rv = (const float*)d_in[8];
    const float* b_rv = (const float*)d_in[9];
    const float* W_o = (const float*)d_in[10];
    const float* b_o = (const float*)d_in[11];
    float* out = (float*)d_out;

    char* ws = (char*)d_ws;
    ushort* P_bf = (ushort*)ws;                          // 4 proj planes, 16.8 MB
    ws += (size_t)4 * PROJ_ELEMS * 2;
    float* bias_cat = (float*)ws;                        // 1280 f32
    ws += 1280 * 4;
    ushort* state_bf = (ushort*)ws;                      // 4 MB
    ws += (size_t)M * D * 2;
    ushort* Wcat = (ushort*)ws;                          // 0.65 MB
    ws += (size_t)1280 * 256 * 2;
    ushort* xbuf_bf = (ushort*)ws;                       // 4 MB

    cast_all<<<2368, 256, 0, stream>>>(state, W_lk, W_rk, W_lv, W_rv, W_o,
                                       b_lk, b_rk, b_lv, b_rv, b_o,
                                       state_bf, Wcat, bias_cat);
    gemm_mfma<1, 1><<<dim3(M / 128, 8), 256, 0, stream>>>(state_bf, Wcat, bias_cat, P_bf, 1024);
    fused_attn<<<dim3(4, 4, B * H), 512, 0, stream>>>(P_bf, mask, xbuf_bf);
    gemm_mfma<0, 0><<<dim3(M / 128, 2), 256, 0, stream>>>(xbuf_bf, Wcat + 1024 * 256, bias_cat + 1024, out, 256);
}

// Round 13
// 129.535 us; speedup vs baseline: 1.0295x; 1.0295x over previous
//
#include <hip/hip_runtime.h>

#define B 2
#define N 64
#define D 256
#define H 8
#define DK 32
#define M (B * N * N) // 8192

typedef __attribute__((ext_vector_type(8))) short bf16x8;
typedef __attribute__((ext_vector_type(4))) float f32x4;

// P is head-major: 4 proj planes of [b][h][r1*64+r2][32] bf16
#define PROJ_ELEMS (2097152)  // B*H*4096*32

__device__ __forceinline__ ushort f2b(float f) {
    union { float f; unsigned u; } v; v.f = f;
    unsigned r = v.u + 0x7fffu + ((v.u >> 16) & 1u); // RNE
    return (ushort)(r >> 16);
}
__device__ __forceinline__ float b2f(ushort u) {
    union { unsigned u; float f; } v; v.u = ((unsigned)u) << 16; return v.f;
}
// convert 8 bf16 (packed in a float4 register) to 8 floats
__device__ __forceinline__ void cvt8(float4 raw, float* f) {
    const ushort* s = (const ushort*)&raw;
#pragma unroll
    for (int j = 0; j < 8; ++j) f[j] = b2f(s[j]);
}

// async 16B/lane global->LDS (dst = wave-uniform base + lane*16)
__device__ __forceinline__ void glds16(const ushort* g, ushort* l) {
    __builtin_amdgcn_global_load_lds(
        (const __attribute__((address_space(1))) unsigned int*)g,
        (__attribute__((address_space(3))) unsigned int*)l, 16, 0, 0);
}

// pack 8 f32 (two float4) -> 8 bf16 in a float4-shaped register
__device__ __forceinline__ float4 pk8(float4 v0, float4 v1) {
    union { ushort us[8]; float4 f4; } pk;
    pk.us[0] = f2b(v0.x); pk.us[1] = f2b(v0.y); pk.us[2] = f2b(v0.z); pk.us[3] = f2b(v0.w);
    pk.us[4] = f2b(v1.x); pk.us[5] = f2b(v1.y); pk.us[6] = f2b(v1.z); pk.us[7] = f2b(v1.w);
    return pk.f4;
}

// ---------------------------------------------------------------------------
// bf16 MFMA GEMM with FUSED f32->bf16 cast in staging. 128x128 tile, 4 waves,
// 4x4 16x16x32 frags, BK=32, K=256.
//   A: AF32=1 -> load f32, cvt, ds_write (cast fused); AF32=0 -> bf16 glds16.
//   B: always f32 source, selected from 4 weight planes by row>>8 (L2-hot).
//   bias: selected from 4 plane biases by col>>8.
//   RELAYOUT=1: scatter bf16 C into head-major P planes; else f32 row-major.
// ---------------------------------------------------------------------------
template <int AF32, int RELAYOUT>
__global__ __launch_bounds__(256) void gemm_mfma(const float* __restrict__ A32,
                                                 const ushort* __restrict__ A16,
                                                 const float* __restrict__ Wb0, const float* __restrict__ Wb1,
                                                 const float* __restrict__ Wb2, const float* __restrict__ Wb3,
                                                 const float* __restrict__ bias0, const float* __restrict__ bias1,
                                                 const float* __restrict__ bias2, const float* __restrict__ bias3,
                                                 void* __restrict__ Cv, int ldc) {
    __shared__ __align__(16) ushort As[128 * 32];
    __shared__ __align__(16) ushort Bs[128 * 32];
    const int tid = threadIdx.x;
    const int lane = tid & 63;
    const int wave = tid >> 6;
    const int wm = (wave & 1) * 64;
    const int wn = (wave >> 1) * 64;
    const int row0 = blockIdx.x * 128;
    const int col0 = blockIdx.y * 128;

    const int lr = lane >> 2;        // 0..15: row within 16-row segment
    const int lkq = (lane & 3) * 8;  // element k-offset {0,8,16,24}

    // ---- staging bases ----
    // A (f32 path): rows row0 + wave*32 + {0,16} + lr
    const float* gA32a = A32 + (size_t)(row0 + wave * 32 + lr) * 256 + lkq;
    const float* gA32b = gA32a + 16 * 256;
    // A (bf16 path)
    const ushort* gA16a = A16 + (size_t)(row0 + wave * 32 + lr) * 256 + lkq;
    const ushort* gA16b = gA16a + 16 * 256;
    // B: rows col0 + wave*32 + {0,16} + lr, plane-selected (uniform per block/wave)
    const float* WB[4] = {Wb0, Wb1, Wb2, Wb3};
    const int brow0 = col0 + wave * 32;
    const float* gWa = WB[brow0 >> 8] + (size_t)((brow0 & 255) + lr) * 256 + lkq;
    const float* gWb = gWa + 16 * 256;
    // LDS dsts
    ushort* lAa = &As[(wave * 32 + lr) * 32 + lkq];
    ushort* lAb = lAa + 16 * 32;
    ushort* lA0 = &As[(wave * 32) * 32];         // glds16 wave-uniform bases
    ushort* lA1 = &As[(wave * 32 + 16) * 32];
    ushort* lBa = &Bs[(wave * 32 + lr) * 32 + lkq];
    ushort* lBb = lBa + 16 * 32;

    const int fr = lane & 15;
    const int fk = (lane >> 4) * 8;

    f32x4 acc[4][4] = {};

    for (int k0 = 0; k0 < 256; k0 += 32) {
        // load next tiles (f32 sources) before the barrier
        float4 wa0 = *(const float4*)(gWa + k0), wa1 = *(const float4*)(gWa + k0 + 4);
        float4 wb0 = *(const float4*)(gWb + k0), wb1 = *(const float4*)(gWb + k0 + 4);
        float4 aa0, aa1, ab0, ab1;
        if (AF32) {
            aa0 = *(const float4*)(gA32a + k0); aa1 = *(const float4*)(gA32a + k0 + 4);
            ab0 = *(const float4*)(gA32b + k0); ab1 = *(const float4*)(gA32b + k0 + 4);
        }
        __syncthreads();
        if (AF32) {
            *(float4*)lAa = pk8(aa0, aa1);
            *(float4*)lAb = pk8(ab0, ab1);
        } else {
            glds16(gA16a + k0, lA0);
            glds16(gA16b + k0, lA1);
        }
        *(float4*)lBa = pk8(wa0, wa1);
        *(float4*)lBb = pk8(wb0, wb1);
        __syncthreads();

        bf16x8 af[4], bf[4];
#pragma unroll
        for (int i = 0; i < 4; ++i)
            af[i] = *(const bf16x8*)&As[(wm + i * 16 + fr) * 32 + fk];
#pragma unroll
        for (int j = 0; j < 4; ++j)
            bf[j] = *(const bf16x8*)&Bs[(wn + j * 16 + fr) * 32 + fk];
#pragma unroll
        for (int i = 0; i < 4; ++i)
#pragma unroll
            for (int j = 0; j < 4; ++j)
                acc[i][j] = __builtin_amdgcn_mfma_f32_16x16x32_bf16(af[i], bf[j], acc[i][j], 0, 0, 0);
    }

    const float* BS[4] = {bias0, bias1, bias2, bias3};
#pragma unroll
    for (int j = 0; j < 4; ++j) {
        const int col = col0 + wn + j * 16 + (lane & 15);
        const float bv = BS[col >> 8][col & 255];
#pragma unroll
        for (int i = 0; i < 4; ++i) {
            const int rbase = row0 + wm + i * 16 + (lane >> 4) * 4;
#pragma unroll
            for (int r = 0; r < 4; ++r) {
                float o = acc[i][j][r] + bv;
                if (RELAYOUT) {
                    const int row = rbase + r;
                    const int bb = row >> 12, rr = row & 4095;
                    const int proj = col >> 8, hh = (col >> 5) & 7, dk = col & 31;
                    ((ushort*)Cv)[(size_t)proj * PROJ_ELEMS +
                                  ((size_t)(bb * 8 + hh) * 4096 + rr) * 32 + dk] = f2b(o);
                } else {
                    ((float*)Cv)[(size_t)(rbase + r) * ldc + col] = o;
                }
            }
        }
    }
}

// ---------------------------------------------------------------------------
// FUSED scores + online-softmax + gated combine, v5 (R10 best — verbatim).
// Tile = 16x x 16y per (b,h); grid (4,4,16) = 256 blocks, 512 threads (8 waves).
// a-chunk = 16, 3 barriers/chunk. P head-major -> contiguous reads.
// LK/RK: per-lane 16B global loads ARE the MFMA A/B frags. No prefetch
// pipeline (R12 lesson: it raises VGPR and moves vmcnt into the gate).
// LDS (~112 KB, 1 block/CU): LVs/RVs f32 [16a][16r][44]; atts [16a][16x][20y].
// ---------------------------------------------------------------------------
__global__ __launch_bounds__(512) void fused_attn(const ushort* __restrict__ P,
                                                  const unsigned char* __restrict__ mask,
                                                  ushort* __restrict__ xbuf) {
    __shared__ __align__(16) float LVs[16 * 16 * 44];
    __shared__ __align__(16) float RVs[16 * 16 * 44];
    __shared__ __align__(16) float atts[16 * 16 * 20];
    __shared__ float mstate[16 * 20];
    __shared__ float lstate[16 * 20];
    __shared__ float alphas[16 * 20];

    const int bh = blockIdx.z;
    const int b = bh >> 3, h = bh & 7;
    const int x0 = blockIdx.x * 16, y0 = blockIdx.y * 16;
    const int tid = threadIdx.x;
    const int lane = tid & 63, wave = tid >> 6;

    const size_t HB = (size_t)bh * 4096 * 32;   // head slice offset (elements)
    const ushort* PLK = P + HB;
    const ushort* PRK = P + (size_t)1 * PROJ_ELEMS + HB;
    const ushort* PLV = P + (size_t)2 * PROJ_ELEMS + HB;
    const ushort* PRV = P + (size_t)3 * PROJ_ELEMS + HB;

    // gate coords: x = wave*2 + i, y = y2*4 + j, d = 2*dp + {0,1}
    const int y2 = (tid >> 4) & 3, dp = tid & 15;
    // softmax coords (threads 0..255)
    const int sx = tid >> 4, sy = tid & 15;
    if (tid < 256) {
        mstate[sx * 20 + sy] = -3.0e38f;
        lstate[sx * 20 + sy] = 0.0f;
    }

    float2 acc[2][4] = {};
    const float scale = 0.17677669529663687f; // 1/sqrt(32)

    for (int ac = 0; ac < N; ac += 16) {
        __syncthreads();
        // ---- phase 1a: stage LV/RV (f32, conflict-audited stride 44) ----
#pragma unroll
        for (int it = 0; it < 2; ++it) {
            const int row = (tid >> 2) + it * 128;  // a*16 + r
            const int q = tid & 3;
            const int a = row >> 4, r = row & 15;
            float f[8];
            cvt8(*(const float4*)&PLV[((size_t)(x0 + r) * 64 + ac + a) * 32 + q * 8], f);
            *(float4*)&LVs[row * 44 + q * 8]     = make_float4(f[0], f[1], f[2], f[3]);
            *(float4*)&LVs[row * 44 + q * 8 + 4] = make_float4(f[4], f[5], f[6], f[7]);
            cvt8(*(const float4*)&PRV[((size_t)(ac + a) * 64 + y0 + r) * 32 + q * 8], f);
            *(float4*)&RVs[row * 44 + q * 8]     = make_float4(f[0], f[1], f[2], f[3]);
            *(float4*)&RVs[row * 44 + q * 8 + 4] = make_float4(f[4], f[5], f[6], f[7]);
        }
        // ---- phase 1b: scores — direct global frags + MFMA, mask direct ----
        {
            const int fr = lane & 15, fk = (lane >> 4) * 8;
            const int yq = lane & 15, xq = (lane >> 4) * 4;
#pragma unroll
            for (int aw = 0; aw < 2; ++aw) {
                const int a = wave * 2 + aw;
                bf16x8 af = *(const bf16x8*)&PLK[((size_t)(x0 + fr) * 64 + ac + a) * 32 + fk];
                bf16x8 bf = *(const bf16x8*)&PRK[((size_t)(ac + a) * 64 + y0 + fr) * 32 + fk];
                f32x4 s = {};
                s = __builtin_amdgcn_mfma_f32_16x16x32_bf16(af, bf, s, 0, 0, 0);
#pragma unroll
                for (int rr = 0; rr < 4; ++rr) {
                    const int x = xq + rr;
                    float sv = s[rr] * scale;
                    if (mask[((size_t)(b * N + x0 + x) * N + ac + a) * N + y0 + yq]) sv = -1000.0f;
                    atts[(a * 16 + x) * 20 + yq] = sv;
                }
            }
        }
        __syncthreads();

        // ---- online softmax over 16-a chunk: threads 0..255 own (sx, sy) ----
        if (tid < 256) {
            float s16[16];
            float mc = -3.0e38f;
#pragma unroll
            for (int a = 0; a < 16; ++a) {
                s16[a] = atts[(a * 16 + sx) * 20 + sy];
                mc = fmaxf(mc, s16[a]);
            }
            const float mold = mstate[sx * 20 + sy];
            const float mnew = fmaxf(mold, mc);
            const float alpha = __expf(mold - mnew);
            float ps = 0.0f;
#pragma unroll
            for (int a = 0; a < 16; ++a) {
                float p = __expf(s16[a] - mnew);
                atts[(a * 16 + sx) * 20 + sy] = p;
                ps += p;
            }
            lstate[sx * 20 + sy] = lstate[sx * 20 + sy] * alpha + ps;
            mstate[sx * 20 + sy] = mnew;
            alphas[sx * 20 + sy] = alpha;
        }
        __syncthreads();

        // ---- rescale + gate ----
#pragma unroll
        for (int i = 0; i < 2; ++i) {
            const int x = wave * 2 + i;
            float4 av = *(const float4*)&alphas[x * 20 + y2 * 4];
            const float* ap = (const float*)&av;
#pragma unroll
            for (int j = 0; j < 4; ++j) {
                acc[i][j].x *= ap[j];
                acc[i][j].y *= ap[j];
            }
        }
#pragma unroll
        for (int a = 0; a < 16; ++a) {
            float2 lv[2], rv[4];
#pragma unroll
            for (int i = 0; i < 2; ++i)
                lv[i] = *(const float2*)&LVs[(a * 16 + wave * 2 + i) * 44 + dp * 2];
#pragma unroll
            for (int j = 0; j < 4; ++j)
                rv[j] = *(const float2*)&RVs[(a * 16 + y2 * 4 + j) * 44 + dp * 2];
#pragma unroll
            for (int i = 0; i < 2; ++i) {
                float4 wv = *(const float4*)&atts[(a * 16 + wave * 2 + i) * 20 + y2 * 4];
                const float* wp = (const float*)&wv;
#pragma unroll
                for (int j = 0; j < 4; ++j) {
                    acc[i][j].x += (wp[j] * lv[i].x) * rv[j].x;
                    acc[i][j].y += (wp[j] * lv[i].y) * rv[j].y;
                }
            }
        }
    }

    // ---- epilogue: divide by l, store bf16 ----
#pragma unroll
    for (int i = 0; i < 2; ++i) {
        const int x = wave * 2 + i;
        float4 lq = *(const float4*)&lstate[x * 20 + y2 * 4];
        const float* lp = (const float*)&lq;
#pragma unroll
        for (int j = 0; j < 4; ++j) {
            const float il = 1.0f / lp[j];
            ushort2 o = {f2b(acc[i][j].x * il), f2b(acc[i][j].y * il)};
            *(ushort2*)&xbuf[(((size_t)b * N + x0 + x) * N + y0 + y2 * 4 + j) * D + h * DK + 2 * dp] = o;
        }
    }
}

// ---------------------------------------------------------------------------
extern "C" void kernel_launch(void* const* d_in, const int* in_sizes, int n_in,
                              void* d_out, int out_size, void* d_ws, size_t ws_size,
                              hipStream_t stream) {
    const float* state = (const float*)d_in[0];
    const unsigned char* mask = (const unsigned char*)d_in[1];
    const float* W_lk = (const float*)d_in[2];
    const float* b_lk = (const float*)d_in[3];
    const float* W_rk = (const float*)d_in[4];
    const float* b_rk = (const float*)d_in[5];
    const float* W_lv = (const float*)d_in[6];
    const float* b_lv = (const float*)d_in[7];
    const float* W_rv = (const float*)d_in[8];
    const float* b_rv = (const float*)d_in[9];
    const float* W_o = (const float*)d_in[10];
    const float* b_o = (const float*)d_in[11];
    float* out = (float*)d_out;

    char* ws = (char*)d_ws;
    ushort* P_bf = (ushort*)ws;                          // 4 proj planes, 16.8 MB
    ws += (size_t)4 * PROJ_ELEMS * 2;
    ushort* xbuf_bf = (ushort*)ws;                       // 4 MB

    // projections: A = state f32 (cast fused into staging), B = 4 weight planes
    gemm_mfma<1, 1><<<dim3(M / 128, 8), 256, 0, stream>>>(
        state, nullptr, W_lk, W_rk, W_lv, W_rv,
        b_lk, b_rk, b_lv, b_rv, P_bf, 1024);
    fused_attn<<<dim3(4, 4, B * H), 512, 0, stream>>>(P_bf, mask, xbuf_bf);
    // output proj: A = xbuf bf16 (glds16), B = W_o f32 (cast fused)
    gemm_mfma<0, 0><<<dim3(M / 128, 2), 256, 0, stream>>>(
        nullptr, xbuf_bf, W_o, W_o, W_o, W_o,
        b_o, b_o, b_o, b_o, out, 256);
}

// Round 14
// 125.476 us; speedup vs baseline: 1.0628x; 1.0323x over previous
//
#include <hip/hip_runtime.h>

#define B 2
#define N 64
#define D 256
#define H 8
#define DK 32
#define M (B * N * N) // 8192

typedef __attribute__((ext_vector_type(8))) short bf16x8;
typedef __attribute__((ext_vector_type(4))) float f32x4;

// P is head-major: 4 proj planes of [b][h][r1*64+r2][32] bf16
#define PROJ_ELEMS (2097152)  // B*H*4096*32

__device__ __forceinline__ ushort f2b(float f) {
    union { float f; unsigned u; } v; v.f = f;
    unsigned r = v.u + 0x7fffu + ((v.u >> 16) & 1u); // RNE
    return (ushort)(r >> 16);
}
__device__ __forceinline__ float b2f(ushort u) {
    union { unsigned u; float f; } v; v.u = ((unsigned)u) << 16; return v.f;
}
// convert 8 bf16 (packed in a float4 register) to 8 floats
__device__ __forceinline__ void cvt8(float4 raw, float* f) {
    const ushort* s = (const ushort*)&raw;
#pragma unroll
    for (int j = 0; j < 8; ++j) f[j] = b2f(s[j]);
}

// async 16B/lane global->LDS (dst = wave-uniform base + lane*16)
__device__ __forceinline__ void glds16(const ushort* g, ushort* l) {
    __builtin_amdgcn_global_load_lds(
        (const __attribute__((address_space(1))) unsigned int*)g,
        (__attribute__((address_space(3))) unsigned int*)l, 16, 0, 0);
}

// ---------------------------------------------------------------------------
// Cast: state f32 -> bf16; 5 weights -> Wcat[1280][256] bf16; biases -> f32.
// Kept as a separate pass ON PURPOSE (R13 lesson): the bf16 A-operand is
// re-read by 8 column-tile blocks in the proj GEMM; casting once keeps that
// re-read at 4 MB instead of 33.5 MB f32.
// ---------------------------------------------------------------------------
__global__ __launch_bounds__(256) void cast_all(const float* __restrict__ state,
                                                const float* __restrict__ W_lk, const float* __restrict__ W_rk,
                                                const float* __restrict__ W_lv, const float* __restrict__ W_rv,
                                                const float* __restrict__ W_o,
                                                const float* __restrict__ b_lk, const float* __restrict__ b_rk,
                                                const float* __restrict__ b_lv, const float* __restrict__ b_rv,
                                                const float* __restrict__ b_o,
                                                ushort* __restrict__ state_bf,
                                                ushort* __restrict__ Wcat,
                                                float* __restrict__ bias_cat) {
    const int gid = blockIdx.x * 256 + threadIdx.x;
    const float* Ws[5] = {W_lk, W_rk, W_lv, W_rv, W_o};
    const float* bs[5] = {b_lk, b_rk, b_lv, b_rv, b_o};

    if (gid < 1280) bias_cat[gid] = bs[gid >> 8][gid & 255];

    if (gid < 524288) {
        float4 v = *(const float4*)&state[(size_t)gid * 4];
        ushort4 o = {f2b(v.x), f2b(v.y), f2b(v.z), f2b(v.w)};
        *(ushort4*)&state_bf[(size_t)gid * 4] = o;
    } else {
        int u = gid - 524288;            // 0..81919
        int row = u >> 6;                // 0..1279
        int k4 = (u & 63) * 4;
        const float* W = Ws[row >> 8];
        float4 v = *(const float4*)&W[(size_t)(row & 255) * 256 + k4];
        ushort4 o = {f2b(v.x), f2b(v.y), f2b(v.z), f2b(v.w)};
        *(ushort4*)&Wcat[(size_t)row * 256 + k4] = o;
    }
}

// ---------------------------------------------------------------------------
// bf16 MFMA GEMM, m97-style. 128x128 tile, 4 waves, 4x4 16x16x32 frags, BK=32.
// RELAYOUT=1 (proj): scatter C into head-major P planes.
// ---------------------------------------------------------------------------
template <int BF16OUT, int RELAYOUT>
__global__ __launch_bounds__(256) void gemm_mfma(const ushort* __restrict__ A,
                                                 const ushort* __restrict__ Bw,
                                                 const float* __restrict__ bias,
                                                 void* __restrict__ Cv, int ldc) {
    __shared__ __align__(16) ushort As[128 * 32];
    __shared__ __align__(16) ushort Bs[128 * 32];
    const int tid = threadIdx.x;
    const int lane = tid & 63;
    const int wave = tid >> 6;
    const int wm = (wave & 1) * 64;
    const int wn = (wave >> 1) * 64;
    const int row0 = blockIdx.x * 128;
    const int col0 = blockIdx.y * 128;

    const int lr = lane >> 2;        // 0..15
    const int lkq = (lane & 3) * 8;  // {0,8,16,24}

    const ushort* gA0 = A + (size_t)(row0 + wave * 32 + lr) * 256 + lkq;
    const ushort* gA1 = gA0 + 16 * 256;
    const ushort* gB0 = Bw + (size_t)(col0 + wave * 32 + lr) * 256 + lkq;
    const ushort* gB1 = gB0 + 16 * 256;
    ushort* lA0 = &As[(wave * 32) * 32];
    ushort* lA1 = &As[(wave * 32 + 16) * 32];
    ushort* lB0 = &Bs[(wave * 32) * 32];
    ushort* lB1 = &Bs[(wave * 32 + 16) * 32];

    const int fr = lane & 15;
    const int fk = (lane >> 4) * 8;

    f32x4 acc[4][4] = {};

    for (int k0 = 0; k0 < 256; k0 += 32) {
        __syncthreads();
        glds16(gA0 + k0, lA0);
        glds16(gA1 + k0, lA1);
        glds16(gB0 + k0, lB0);
        glds16(gB1 + k0, lB1);
        __syncthreads();

        bf16x8 af[4], bf[4];
#pragma unroll
        for (int i = 0; i < 4; ++i)
            af[i] = *(const bf16x8*)&As[(wm + i * 16 + fr) * 32 + fk];
#pragma unroll
        for (int j = 0; j < 4; ++j)
            bf[j] = *(const bf16x8*)&Bs[(wn + j * 16 + fr) * 32 + fk];
#pragma unroll
        for (int i = 0; i < 4; ++i)
#pragma unroll
            for (int j = 0; j < 4; ++j)
                acc[i][j] = __builtin_amdgcn_mfma_f32_16x16x32_bf16(af[i], bf[j], acc[i][j], 0, 0, 0);
    }

#pragma unroll
    for (int j = 0; j < 4; ++j) {
        const int col = col0 + wn + j * 16 + (lane & 15);
        const float bv = bias[col];
#pragma unroll
        for (int i = 0; i < 4; ++i) {
            const int rbase = row0 + wm + i * 16 + (lane >> 4) * 4;
#pragma unroll
            for (int r = 0; r < 4; ++r) {
                float o = acc[i][j][r] + bv;
                if (RELAYOUT) {
                    const int row = rbase + r;
                    const int bb = row >> 12, rr = row & 4095;
                    const int proj = col >> 8, hh = (col >> 5) & 7, dk = col & 31;
                    ((ushort*)Cv)[(size_t)proj * PROJ_ELEMS +
                                  ((size_t)(bb * 8 + hh) * 4096 + rr) * 32 + dk] = f2b(o);
                } else if (BF16OUT) {
                    ((ushort*)Cv)[(size_t)(rbase + r) * ldc + col] = f2b(o);
                } else {
                    ((float*)Cv)[(size_t)(rbase + r) * ldc + col] = o;
                }
            }
        }
    }
}

// ---------------------------------------------------------------------------
// FUSED scores + online-softmax + gated combine, v5 (R10 best — verbatim).
// Tile = 16x x 16y per (b,h); grid (4,4,16) = 256 blocks, 512 threads (8 waves).
// a-chunk = 16, 3 barriers/chunk. P head-major -> contiguous reads.
// LK/RK: per-lane 16B global loads ARE the MFMA A/B frags.
// No register prefetch pipeline (R12 lesson), no tile split (R11 lesson),
// no launch_bounds min-waves (R9 lesson).
// LDS (~112 KB, 1 block/CU): LVs/RVs f32 [16a][16r][44]; atts [16a][16x][20y].
// ---------------------------------------------------------------------------
__global__ __launch_bounds__(512) void fused_attn(const ushort* __restrict__ P,
                                                  const unsigned char* __restrict__ mask,
                                                  ushort* __restrict__ xbuf) {
    __shared__ __align__(16) float LVs[16 * 16 * 44];
    __shared__ __align__(16) float RVs[16 * 16 * 44];
    __shared__ __align__(16) float atts[16 * 16 * 20];
    __shared__ float mstate[16 * 20];
    __shared__ float lstate[16 * 20];
    __shared__ float alphas[16 * 20];

    const int bh = blockIdx.z;
    const int b = bh >> 3, h = bh & 7;
    const int x0 = blockIdx.x * 16, y0 = blockIdx.y * 16;
    const int tid = threadIdx.x;
    const int lane = tid & 63, wave = tid >> 6;

    const size_t HB = (size_t)bh * 4096 * 32;   // head slice offset (elements)
    const ushort* PLK = P + HB;
    const ushort* PRK = P + (size_t)1 * PROJ_ELEMS + HB;
    const ushort* PLV = P + (size_t)2 * PROJ_ELEMS + HB;
    const ushort* PRV = P + (size_t)3 * PROJ_ELEMS + HB;

    // gate coords: x = wave*2 + i, y = y2*4 + j, d = 2*dp + {0,1}
    const int y2 = (tid >> 4) & 3, dp = tid & 15;
    // softmax coords (threads 0..255)
    const int sx = tid >> 4, sy = tid & 15;
    if (tid < 256) {
        mstate[sx * 20 + sy] = -3.0e38f;
        lstate[sx * 20 + sy] = 0.0f;
    }

    float2 acc[2][4] = {};
    const float scale = 0.17677669529663687f; // 1/sqrt(32)

    for (int ac = 0; ac < N; ac += 16) {
        __syncthreads();
        // ---- phase 1a: stage LV/RV (f32, conflict-audited stride 44) ----
#pragma unroll
        for (int it = 0; it < 2; ++it) {
            const int row = (tid >> 2) + it * 128;  // a*16 + r
            const int q = tid & 3;
            const int a = row >> 4, r = row & 15;
            float f[8];
            cvt8(*(const float4*)&PLV[((size_t)(x0 + r) * 64 + ac + a) * 32 + q * 8], f);
            *(float4*)&LVs[row * 44 + q * 8]     = make_float4(f[0], f[1], f[2], f[3]);
            *(float4*)&LVs[row * 44 + q * 8 + 4] = make_float4(f[4], f[5], f[6], f[7]);
            cvt8(*(const float4*)&PRV[((size_t)(ac + a) * 64 + y0 + r) * 32 + q * 8], f);
            *(float4*)&RVs[row * 44 + q * 8]     = make_float4(f[0], f[1], f[2], f[3]);
            *(float4*)&RVs[row * 44 + q * 8 + 4] = make_float4(f[4], f[5], f[6], f[7]);
        }
        // ---- phase 1b: scores — direct global frags + MFMA, mask direct ----
        {
            const int fr = lane & 15, fk = (lane >> 4) * 8;
            const int yq = lane & 15, xq = (lane >> 4) * 4;
#pragma unroll
            for (int aw = 0; aw < 2; ++aw) {
                const int a = wave * 2 + aw;
                bf16x8 af = *(const bf16x8*)&PLK[((size_t)(x0 + fr) * 64 + ac + a) * 32 + fk];
                bf16x8 bf = *(const bf16x8*)&PRK[((size_t)(ac + a) * 64 + y0 + fr) * 32 + fk];
                f32x4 s = {};
                s = __builtin_amdgcn_mfma_f32_16x16x32_bf16(af, bf, s, 0, 0, 0);
#pragma unroll
                for (int rr = 0; rr < 4; ++rr) {
                    const int x = xq + rr;
                    float sv = s[rr] * scale;
                    if (mask[((size_t)(b * N + x0 + x) * N + ac + a) * N + y0 + yq]) sv = -1000.0f;
                    atts[(a * 16 + x) * 20 + yq] = sv;
                }
            }
        }
        __syncthreads();

        // ---- online softmax over 16-a chunk: threads 0..255 own (sx, sy) ----
        if (tid < 256) {
            float s16[16];
            float mc = -3.0e38f;
#pragma unroll
            for (int a = 0; a < 16; ++a) {
                s16[a] = atts[(a * 16 + sx) * 20 + sy];
                mc = fmaxf(mc, s16[a]);
            }
            const float mold = mstate[sx * 20 + sy];
            const float mnew = fmaxf(mold, mc);
            const float alpha = __expf(mold - mnew);
            float ps = 0.0f;
#pragma unroll
            for (int a = 0; a < 16; ++a) {
                float p = __expf(s16[a] - mnew);
                atts[(a * 16 + sx) * 20 + sy] = p;
                ps += p;
            }
            lstate[sx * 20 + sy] = lstate[sx * 20 + sy] * alpha + ps;
            mstate[sx * 20 + sy] = mnew;
            alphas[sx * 20 + sy] = alpha;
        }
        __syncthreads();

        // ---- rescale + gate ----
#pragma unroll
        for (int i = 0; i < 2; ++i) {
            const int x = wave * 2 + i;
            float4 av = *(const float4*)&alphas[x * 20 + y2 * 4];
            const float* ap = (const float*)&av;
#pragma unroll
            for (int j = 0; j < 4; ++j) {
                acc[i][j].x *= ap[j];
                acc[i][j].y *= ap[j];
            }
        }
#pragma unroll
        for (int a = 0; a < 16; ++a) {
            float2 lv[2], rv[4];
#pragma unroll
            for (int i = 0; i < 2; ++i)
                lv[i] = *(const float2*)&LVs[(a * 16 + wave * 2 + i) * 44 + dp * 2];
#pragma unroll
            for (int j = 0; j < 4; ++j)
                rv[j] = *(const float2*)&RVs[(a * 16 + y2 * 4 + j) * 44 + dp * 2];
#pragma unroll
            for (int i = 0; i < 2; ++i) {
                float4 wv = *(const float4*)&atts[(a * 16 + wave * 2 + i) * 20 + y2 * 4];
                const float* wp = (const float*)&wv;
#pragma unroll
                for (int j = 0; j < 4; ++j) {
                    acc[i][j].x += (wp[j] * lv[i].x) * rv[j].x;
                    acc[i][j].y += (wp[j] * lv[i].y) * rv[j].y;
                }
            }
        }
    }

    // ---- epilogue: divide by l, store bf16 ----
#pragma unroll
    for (int i = 0; i < 2; ++i) {
        const int x = wave * 2 + i;
        float4 lq = *(const float4*)&lstate[x * 20 + y2 * 4];
        const float* lp = (const float*)&lq;
#pragma unroll
        for (int j = 0; j < 4; ++j) {
            const float il = 1.0f / lp[j];
            ushort2 o = {f2b(acc[i][j].x * il), f2b(acc[i][j].y * il)};
            *(ushort2*)&xbuf[(((size_t)b * N + x0 + x) * N + y0 + y2 * 4 + j) * D + h * DK + 2 * dp] = o;
        }
    }
}

// ---------------------------------------------------------------------------
extern "C" void kernel_launch(void* const* d_in, const int* in_sizes, int n_in,
                              void* d_out, int out_size, void* d_ws, size_t ws_size,
                              hipStream_t stream) {
    const float* state = (const float*)d_in[0];
    const unsigned char* mask = (const unsigned char*)d_in[1];
    const float* W_lk = (const float*)d_in[2];
    const float* b_lk = (const float*)d_in[3];
    const float* W_rk = (const float*)d_in[4];
    const float* b_rk = (const float*)d_in[5];
    const float* W_lv = (const float*)d_in[6];
    const float* b_lv = (const float*)d_in[7];
    const float* W_rv = (const float*)d_in[8];
    const float* b_rv = (const float*)d_in[9];
    const float* W_o = (const float*)d_in[10];
    const float* b_o = (const float*)d_in[11];
    float* out = (float*)d_out;

    char* ws = (char*)d_ws;
    ushort* P_bf = (ushort*)ws;                          // 4 proj planes, 16.8 MB
    ws += (size_t)4 * PROJ_ELEMS * 2;
    float* bias_cat = (float*)ws;                        // 1280 f32
    ws += 1280 * 4;
    ushort* state_bf = (ushort*)ws;                      // 4 MB
    ws += (size_t)M * D * 2;
    ushort* Wcat = (ushort*)ws;                          // 0.65 MB
    ws += (size_t)1280 * 256 * 2;
    ushort* xbuf_bf = (ushort*)ws;                       // 4 MB

    cast_all<<<2368, 256, 0, stream>>>(state, W_lk, W_rk, W_lv, W_rv, W_o,
                                       b_lk, b_rk, b_lv, b_rv, b_o,
                                       state_bf, Wcat, bias_cat);
    gemm_mfma<1, 1><<<dim3(M / 128, 8), 256, 0, stream>>>(state_bf, Wcat, bias_cat, P_bf, 1024);
    fused_attn<<<dim3(4, 4, B * H), 512, 0, stream>>>(P_bf, mask, xbuf_bf);
    gemm_mfma<0, 0><<<dim3(M / 128, 2), 256, 0, stream>>>(xbuf_bf, Wcat + 1024 * 256, bias_cat + 1024, out, 256);
}

// Round 15
// 123.751 us; speedup vs baseline: 1.0776x; 1.0139x over previous
//
#include <hip/hip_runtime.h>

#define B 2
#define N 64
#define D 256
#define H 8
#define DK 32
#define M (B * N * N) // 8192

typedef __attribute__((ext_vector_type(8))) short bf16x8;
typedef __attribute__((ext_vector_type(4))) float f32x4;

// P is head-major: 4 proj planes of [b][h][r1*64+r2][32] bf16
#define PROJ_ELEMS (2097152)  // B*H*4096*32

__device__ __forceinline__ ushort f2b(float f) {
    union { float f; unsigned u; } v; v.f = f;
    unsigned r = v.u + 0x7fffu + ((v.u >> 16) & 1u); // RNE
    return (ushort)(r >> 16);
}
__device__ __forceinline__ float b2f(ushort u) {
    union { unsigned u; float f; } v; v.u = ((unsigned)u) << 16; return v.f;
}
// expand packed ushort2 (as uint) -> two floats
__device__ __forceinline__ float2 up2(unsigned u) {
    union { unsigned u; float f; } lo, hi;
    lo.u = u << 16;
    hi.u = u & 0xffff0000u;
    return make_float2(lo.f, hi.f);
}
// convert 8 bf16 (packed in a float4 register) to 8 floats
__device__ __forceinline__ void cvt8(float4 raw, float* f) {
    const ushort* s = (const ushort*)&raw;
#pragma unroll
    for (int j = 0; j < 8; ++j) f[j] = b2f(s[j]);
}

// async 16B/lane global->LDS (dst = wave-uniform base + lane*16)
__device__ __forceinline__ void glds16(const ushort* g, ushort* l) {
    __builtin_amdgcn_global_load_lds(
        (const __attribute__((address_space(1))) unsigned int*)g,
        (__attribute__((address_space(3))) unsigned int*)l, 16, 0, 0);
}

// ---------------------------------------------------------------------------
// Cast: state f32 -> bf16; 5 weights -> Wcat[1280][256] bf16; biases -> f32.
// Kept as a separate pass (R13 lesson: bf16 A is re-read 8x in the GEMM).
// ---------------------------------------------------------------------------
__global__ __launch_bounds__(256) void cast_all(const float* __restrict__ state,
                                                const float* __restrict__ W_lk, const float* __restrict__ W_rk,
                                                const float* __restrict__ W_lv, const float* __restrict__ W_rv,
                                                const float* __restrict__ W_o,
                                                const float* __restrict__ b_lk, const float* __restrict__ b_rk,
                                                const float* __restrict__ b_lv, const float* __restrict__ b_rv,
                                                const float* __restrict__ b_o,
                                                ushort* __restrict__ state_bf,
                                                ushort* __restrict__ Wcat,
                                                float* __restrict__ bias_cat) {
    const int gid = blockIdx.x * 256 + threadIdx.x;
    const float* Ws[5] = {W_lk, W_rk, W_lv, W_rv, W_o};
    const float* bs[5] = {b_lk, b_rk, b_lv, b_rv, b_o};

    if (gid < 1280) bias_cat[gid] = bs[gid >> 8][gid & 255];

    if (gid < 524288) {
        float4 v = *(const float4*)&state[(size_t)gid * 4];
        ushort4 o = {f2b(v.x), f2b(v.y), f2b(v.z), f2b(v.w)};
        *(ushort4*)&state_bf[(size_t)gid * 4] = o;
    } else {
        int u = gid - 524288;            // 0..81919
        int row = u >> 6;                // 0..1279
        int k4 = (u & 63) * 4;
        const float* W = Ws[row >> 8];
        float4 v = *(const float4*)&W[(size_t)(row & 255) * 256 + k4];
        ushort4 o = {f2b(v.x), f2b(v.y), f2b(v.z), f2b(v.w)};
        *(ushort4*)&Wcat[(size_t)row * 256 + k4] = o;
    }
}

// ---------------------------------------------------------------------------
// bf16 MFMA GEMM, m97-style. 128x128 tile, 4 waves, 4x4 16x16x32 frags, BK=32.
// RELAYOUT=1 (proj): scatter C into head-major P planes.
// ---------------------------------------------------------------------------
template <int BF16OUT, int RELAYOUT>
__global__ __launch_bounds__(256) void gemm_mfma(const ushort* __restrict__ A,
                                                 const ushort* __restrict__ Bw,
                                                 const float* __restrict__ bias,
                                                 void* __restrict__ Cv, int ldc) {
    __shared__ __align__(16) ushort As[128 * 32];
    __shared__ __align__(16) ushort Bs[128 * 32];
    const int tid = threadIdx.x;
    const int lane = tid & 63;
    const int wave = tid >> 6;
    const int wm = (wave & 1) * 64;
    const int wn = (wave >> 1) * 64;
    const int row0 = blockIdx.x * 128;
    const int col0 = blockIdx.y * 128;

    const int lr = lane >> 2;        // 0..15
    const int lkq = (lane & 3) * 8;  // {0,8,16,24}

    const ushort* gA0 = A + (size_t)(row0 + wave * 32 + lr) * 256 + lkq;
    const ushort* gA1 = gA0 + 16 * 256;
    const ushort* gB0 = Bw + (size_t)(col0 + wave * 32 + lr) * 256 + lkq;
    const ushort* gB1 = gB0 + 16 * 256;
    ushort* lA0 = &As[(wave * 32) * 32];
    ushort* lA1 = &As[(wave * 32 + 16) * 32];
    ushort* lB0 = &Bs[(wave * 32) * 32];
    ushort* lB1 = &Bs[(wave * 32 + 16) * 32];

    const int fr = lane & 15;
    const int fk = (lane >> 4) * 8;

    f32x4 acc[4][4] = {};

    for (int k0 = 0; k0 < 256; k0 += 32) {
        __syncthreads();
        glds16(gA0 + k0, lA0);
        glds16(gA1 + k0, lA1);
        glds16(gB0 + k0, lB0);
        glds16(gB1 + k0, lB1);
        __syncthreads();

        bf16x8 af[4], bf[4];
#pragma unroll
        for (int i = 0; i < 4; ++i)
            af[i] = *(const bf16x8*)&As[(wm + i * 16 + fr) * 32 + fk];
#pragma unroll
        for (int j = 0; j < 4; ++j)
            bf[j] = *(const bf16x8*)&Bs[(wn + j * 16 + fr) * 32 + fk];
#pragma unroll
        for (int i = 0; i < 4; ++i)
#pragma unroll
            for (int j = 0; j < 4; ++j)
                acc[i][j] = __builtin_amdgcn_mfma_f32_16x16x32_bf16(af[i], bf[j], acc[i][j], 0, 0, 0);
    }

#pragma unroll
    for (int j = 0; j < 4; ++j) {
        const int col = col0 + wn + j * 16 + (lane & 15);
        const float bv = bias[col];
#pragma unroll
        for (int i = 0; i < 4; ++i) {
            const int rbase = row0 + wm + i * 16 + (lane >> 4) * 4;
#pragma unroll
            for (int r = 0; r < 4; ++r) {
                float o = acc[i][j][r] + bv;
                if (RELAYOUT) {
                    const int row = rbase + r;
                    const int bb = row >> 12, rr = row & 4095;
                    const int proj = col >> 8, hh = (col >> 5) & 7, dk = col & 31;
                    ((ushort*)Cv)[(size_t)proj * PROJ_ELEMS +
                                  ((size_t)(bb * 8 + hh) * 4096 + rr) * 32 + dk] = f2b(o);
                } else if (BF16OUT) {
                    ((ushort*)Cv)[(size_t)(rbase + r) * ldc + col] = f2b(o);
                } else {
                    ((float*)Cv)[(size_t)(rbase + r) * ldc + col] = o;
                }
            }
        }
    }
}

// ---------------------------------------------------------------------------
// FUSED scores + online-softmax + gated combine, v8 = v5 split over d.
// Block owns (16x, 16y, 16d-half) of one (b,h): grid (4,4,32) = 512 blocks,
// 256 threads (4 waves). a-chunk = 16, 3 barriers/chunk.
// LDS ~48 KB -> 2+ blocks/CU RESIDENT (512 blocks / 256 CUs): independent
// blocks hide each other's barrier drains — the v5 1-block/CU pathology.
// LV/RV stay bf16 in LDS (rows padded to 24 ushorts = 48 B; lv reads
// broadcast, rv 2-way = free); cvt to f32 at use in the gate (2 VALU/pair).
// Scores/softmax/mask duplicated across the 2 d-half blocks (cheap).
// No min-waves launch_bounds (R9), no register pipeline (R12).
// ---------------------------------------------------------------------------
__global__ __launch_bounds__(256) void fused_attn(const ushort* __restrict__ P,
                                                  const unsigned char* __restrict__ mask,
                                                  ushort* __restrict__ xbuf) {
    __shared__ __align__(16) ushort LVs[256 * 24];   // [a*16+r][24] bf16, d-half
    __shared__ __align__(16) ushort RVs[256 * 24];   // [a*16+y][24] bf16, d-half
    __shared__ __align__(16) float atts[256 * 20];   // [a*16+x][20] f32
    __shared__ float mstate[16 * 20];
    __shared__ float lstate[16 * 20];
    __shared__ float alphas[16 * 20];

    const int bhz = blockIdx.z;            // 0..31
    const int bh = bhz >> 1, dhalf = bhz & 1;
    const int b = bh >> 3, h = bh & 7;
    const int x0 = blockIdx.x * 16, y0 = blockIdx.y * 16;
    const int tid = threadIdx.x;
    const int lane = tid & 63, wave = tid >> 6;

    const size_t HB = (size_t)bh * 4096 * 32;   // head slice offset (elements)
    const ushort* PLK = P + HB;
    const ushort* PRK = P + (size_t)1 * PROJ_ELEMS + HB;
    const ushort* PLV = P + (size_t)2 * PROJ_ELEMS + HB;
    const ushort* PRV = P + (size_t)3 * PROJ_ELEMS + HB;

    // gate coords: x = xg*2+i, y = y2*4+j, d = dhalf*16 + dp*2 + {0,1}
    const int dp = tid & 7, y2 = (tid >> 3) & 3, xg = tid >> 5;
    // softmax coords: all 256 threads own one (sx, sy)
    const int sx = tid >> 4, sy = tid & 15;
    mstate[sx * 20 + sy] = -3.0e38f;
    lstate[sx * 20 + sy] = 0.0f;

    float2 acc[2][4] = {};
    const float scale = 0.17677669529663687f; // 1/sqrt(32)

    for (int ac = 0; ac < N; ac += 16) {
        __syncthreads();
        // ---- phase 1a: stage LV/RV bf16 d-half (one 32B row per thread) ----
        {
            const int a = tid >> 4, r = tid & 15;
            const ushort* s = &PLV[((size_t)(x0 + r) * 64 + ac + a) * 32 + dhalf * 16];
            *(float4*)&LVs[tid * 24 + 0] = *(const float4*)&s[0];
            *(float4*)&LVs[tid * 24 + 8] = *(const float4*)&s[8];
            const ushort* s2 = &PRV[((size_t)(ac + a) * 64 + y0 + r) * 32 + dhalf * 16];
            *(float4*)&RVs[tid * 24 + 0] = *(const float4*)&s2[0];
            *(float4*)&RVs[tid * 24 + 8] = *(const float4*)&s2[8];
        }
        // ---- phase 1b: scores — direct global frags + MFMA (wave: 4 a's) ----
        {
            const int fr = lane & 15, fk = (lane >> 4) * 8;
            const int yq = lane & 15, xq = (lane >> 4) * 4;
#pragma unroll
            for (int aw = 0; aw < 4; ++aw) {
                const int a = wave * 4 + aw;
                bf16x8 af = *(const bf16x8*)&PLK[((size_t)(x0 + fr) * 64 + ac + a) * 32 + fk];
                bf16x8 bf = *(const bf16x8*)&PRK[((size_t)(ac + a) * 64 + y0 + fr) * 32 + fk];
                f32x4 s = {};
                s = __builtin_amdgcn_mfma_f32_16x16x32_bf16(af, bf, s, 0, 0, 0);
#pragma unroll
                for (int rr = 0; rr < 4; ++rr) {
                    const int x = xq + rr;
                    float sv = s[rr] * scale;
                    if (mask[((size_t)(b * N + x0 + x) * N + ac + a) * N + y0 + yq]) sv = -1000.0f;
                    atts[(a * 16 + x) * 20 + yq] = sv;
                }
            }
        }
        __syncthreads();

        // ---- phase 2: online softmax over 16-a chunk (all 256 threads) ----
        {
            float s16[16];
            float mc = -3.0e38f;
#pragma unroll
            for (int a = 0; a < 16; ++a) {
                s16[a] = atts[(a * 16 + sx) * 20 + sy];
                mc = fmaxf(mc, s16[a]);
            }
            const float mold = mstate[sx * 20 + sy];
            const float mnew = fmaxf(mold, mc);
            const float alpha = __expf(mold - mnew);
            float ps = 0.0f;
#pragma unroll
            for (int a = 0; a < 16; ++a) {
                float p = __expf(s16[a] - mnew);
                atts[(a * 16 + sx) * 20 + sy] = p;
                ps += p;
            }
            lstate[sx * 20 + sy] = lstate[sx * 20 + sy] * alpha + ps;
            mstate[sx * 20 + sy] = mnew;
            alphas[sx * 20 + sy] = alpha;
        }
        __syncthreads();

        // ---- phase 3: rescale + gate: thread (xg:2x, y2:4y, dp:2d) ----
#pragma unroll
        for (int i = 0; i < 2; ++i) {
            float4 av = *(const float4*)&alphas[(xg * 2 + i) * 20 + y2 * 4];
            const float* ap = (const float*)&av;
#pragma unroll
            for (int j = 0; j < 4; ++j) {
                acc[i][j].x *= ap[j];
                acc[i][j].y *= ap[j];
            }
        }
#pragma unroll
        for (int a = 0; a < 16; ++a) {
            float2 lv[2], rv[4];
#pragma unroll
            for (int i = 0; i < 2; ++i)
                lv[i] = up2(*(const unsigned*)&LVs[(a * 16 + xg * 2 + i) * 24 + dp * 2]);
#pragma unroll
            for (int j = 0; j < 4; ++j)
                rv[j] = up2(*(const unsigned*)&RVs[(a * 16 + y2 * 4 + j) * 24 + dp * 2]);
#pragma unroll
            for (int i = 0; i < 2; ++i) {
                float4 wv = *(const float4*)&atts[(a * 16 + xg * 2 + i) * 20 + y2 * 4];
                const float* wp = (const float*)&wv;
#pragma unroll
                for (int j = 0; j < 4; ++j) {
                    acc[i][j].x += (wp[j] * lv[i].x) * rv[j].x;
                    acc[i][j].y += (wp[j] * lv[i].y) * rv[j].y;
                }
            }
        }
    }

    // ---- epilogue: divide by l, store bf16 (d-half) ----
#pragma unroll
    for (int i = 0; i < 2; ++i) {
        const int x = xg * 2 + i;
        float4 lq = *(const float4*)&lstate[x * 20 + y2 * 4];
        const float* lp = (const float*)&lq;
#pragma unroll
        for (int j = 0; j < 4; ++j) {
            const float il = 1.0f / lp[j];
            ushort2 o = {f2b(acc[i][j].x * il), f2b(acc[i][j].y * il)};
            *(ushort2*)&xbuf[(((size_t)b * N + x0 + x) * N + y0 + y2 * 4 + j) * D +
                             h * DK + dhalf * 16 + dp * 2] = o;
        }
    }
}

// ---------------------------------------------------------------------------
extern "C" void kernel_launch(void* const* d_in, const int* in_sizes, int n_in,
                              void* d_out, int out_size, void* d_ws, size_t ws_size,
                              hipStream_t stream) {
    const float* state = (const float*)d_in[0];
    const unsigned char* mask = (const unsigned char*)d_in[1];
    const float* W_lk = (const float*)d_in[2];
    const float* b_lk = (const float*)d_in[3];
    const float* W_rk = (const float*)d_in[4];
    const float* b_rk = (const float*)d_in[5];
    const float* W_lv = (const float*)d_in[6];
    const float* b_lv = (const float*)d_in[7];
    const float* W_rv = (const float*)d_in[8];
    const float* b_rv = (const float*)d_in[9];
    const float* W_o = (const float*)d_in[10];
    const float* b_o = (const float*)d_in[11];
    float* out = (float*)d_out;

    char* ws = (char*)d_ws;
    ushort* P_bf = (ushort*)ws;                          // 4 proj planes, 16.8 MB
    ws += (size_t)4 * PROJ_ELEMS * 2;
    float* bias_cat = (float*)ws;                        // 1280 f32
    ws += 1280 * 4;
    ushort* state_bf = (ushort*)ws;                      // 4 MB
    ws += (size_t)M * D * 2;
    ushort* Wcat = (ushort*)ws;                          // 0.65 MB
    ws += (size_t)1280 * 256 * 2;
    ushort* xbuf_bf = (ushort*)ws;                       // 4 MB

    cast_all<<<2368, 256, 0, stream>>>(state, W_lk, W_rk, W_lv, W_rv, W_o,
                                       b_lk, b_rk, b_lv, b_rv, b_o,
                                       state_bf, Wcat, bias_cat);
    gemm_mfma<1, 1><<<dim3(M / 128, 8), 256, 0, stream>>>(state_bf, Wcat, bias_cat, P_bf, 1024);
    fused_attn<<<dim3(4, 4, B * H * 2), 256, 0, stream>>>(P_bf, mask, xbuf_bf);
    gemm_mfma<0, 0><<<dim3(M / 128, 2), 256, 0, stream>>>(xbuf_bf, Wcat + 1024 * 256, bias_cat + 1024, out, 256);
}